// Round 3
// baseline (59151.776 us; speedup 1.0000x reference)
//
#include <hip/hip_runtime.h>

#define SEQ  8192
#define HID  1024
#define NBLK 64
#define WPB  16            // waves per block
#define TPB  (WPB * 64)    // 1024 threads
#define KCH  (HID / 64)    // 16 K-chunks per dot product

// slots layout in d_ws: 2 parity slots x HID u64 words, each word = (step_tag<<32)|f32bits(h[j])
#define SLOT_WORDS (2 * HID)

__device__ __forceinline__ float sigmoidf_fast(float a) {
    return 1.0f / (1.0f + __expf(-a));   // large |a| saturates cleanly (inf -> 0)
}
__device__ __forceinline__ float tanhf_fast(float a) {
    float t = fabsf(a);
    float e = __expf(-2.0f * t);         // e in (0,1], no overflow
    float r = (1.0f - e) / (1.0f + e);
    return copysignf(r, a);
}

__global__ __launch_bounds__(TPB, 4) void gru_persistent(
    const float* __restrict__ inp,   // [SEQ, HID]
    const float* __restrict__ Wih,   // [3*HID, HID]
    const float* __restrict__ Whh,   // [3*HID, HID]
    const float* __restrict__ bih,   // [3*HID]
    const float* __restrict__ bhh,   // [3*HID]
    float* __restrict__ out,         // [SEQ, HID]
    unsigned long long* __restrict__ slots)  // [2][HID]
{
    __shared__ float h_lds[HID];
    const int tid  = threadIdx.x;
    const int wave = tid >> 6;
    const int lane = tid & 63;
    const int j    = blockIdx.x * WPB + wave;   // this wave's output index, 0..1023

    // ---- persistent W_hh rows (j, HID+j, 2*HID+j) in VGPRs: 48 regs/thread ----
    float wr[KCH], wz[KCH], wn[KCH];
    {
        const float* Wr = Whh + (size_t)j * HID;
        const float* Wz = Whh + (size_t)(HID + j) * HID;
        const float* Wn = Whh + (size_t)(2 * HID + j) * HID;
#pragma unroll
        for (int k = 0; k < KCH; ++k) {
            wr[k] = Wr[lane + 64 * k];
            wz[k] = Wz[lane + 64 * k];
            wn[k] = Wn[lane + 64 * k];
        }
    }
    // biases are added ONCE, after the 64-lane reduction (NOT per-lane!)
    const float bxr = bih[j], bxz = bih[HID + j], bxn = bih[2 * HID + j];
    const float bhr = bhh[j], bhz = bhh[HID + j], bhn = bhh[2 * HID + j];
    const float* Ur = Wih + (size_t)j * HID;              // W_ih rows stay L2-resident
    const float* Uz = Wih + (size_t)(HID + j) * HID;
    const float* Un = Wih + (size_t)(2 * HID + j) * HID;

    // ---- x-side projection for t=1 (software-pipelined one step ahead) ----
    float xr = 0.0f, xz = 0.0f, xn = 0.0f;
    {
        const float* x = inp;   // row 0
#pragma unroll
        for (int k = 0; k < KCH; ++k) {
            float xv = x[lane + 64 * k];
            xr = fmaf(Ur[lane + 64 * k], xv, xr);
            xz = fmaf(Uz[lane + 64 * k], xv, xz);
            xn = fmaf(Un[lane + 64 * k], xv, xn);
        }
#pragma unroll
        for (int m = 32; m >= 1; m >>= 1) {
            xr += __shfl_xor(xr, m, 64);
            xz += __shfl_xor(xz, m, 64);
            xn += __shfl_xor(xn, m, 64);
        }
        xr += bxr; xz += bxz; xn += bxn;
    }

    for (int t = 1; t <= SEQ; ++t) {
        // ---- wave 0: poll previous-parity slot until all 1024 tags == t-1,
        //      values ride in the same 8B atomic load (no second round trip) ----
        unsigned long long* rd = slots + ((t - 1) & 1) * HID;
        if (wave == 0) {
            const unsigned expect = (unsigned)(t - 1);
            for (;;) {
                float v[KCH];
                bool ok = true;
#pragma unroll
                for (int k = 0; k < KCH; ++k) {
                    unsigned long long wv = __hip_atomic_load(
                        rd + lane + 64 * k, __ATOMIC_RELAXED, __HIP_MEMORY_SCOPE_AGENT);
                    ok &= ((unsigned)(wv >> 32) == expect);
                    v[k] = __uint_as_float((unsigned)(wv & 0xffffffffu));
                }
                if (__all(ok)) {
#pragma unroll
                    for (int k = 0; k < KCH; ++k) h_lds[lane + 64 * k] = v[k];
                    break;
                }
                __builtin_amdgcn_s_sleep(1);
            }
        }
        __syncthreads();

        // ---- h-side matvec from persistent VGPR weights, h from LDS ----
        float hr = 0.0f, hz = 0.0f, hn = 0.0f;
#pragma unroll
        for (int k = 0; k < KCH; ++k) {
            float hv = h_lds[lane + 64 * k];
            hr = fmaf(wr[k], hv, hr);
            hz = fmaf(wz[k], hv, hz);
            hn = fmaf(wn[k], hv, hn);
        }
#pragma unroll
        for (int m = 32; m >= 1; m >>= 1) {
            hr += __shfl_xor(hr, m, 64);
            hz += __shfl_xor(hz, m, 64);
            hn += __shfl_xor(hn, m, 64);
        }
        hr += bhr; hz += bhz; hn += bhn;

        const float hprev = h_lds[j];
        const float r = sigmoidf_fast(xr + hr);
        const float z = sigmoidf_fast(xz + hz);
        const float n = tanhf_fast(xn + r * hn);   // r gates the hidden candidate (incl. b_hh_n)
        const float hnew = (1.0f - z) * n + z * hprev;

        if (lane == 0) {
            // publish FIRST — this is what every other block's critical path waits on
            unsigned long long pub = ((unsigned long long)(unsigned)t << 32)
                                   | (unsigned long long)__float_as_uint(hnew);
            __hip_atomic_store(slots + (t & 1) * HID + j, pub,
                               __ATOMIC_RELAXED, __HIP_MEMORY_SCOPE_AGENT);
            // out is write-only streaming: keep it out of L2/L3 hot lines
            __builtin_nontemporal_store(hnew, out + (size_t)(t - 1) * HID + j);
        }

        // ---- x-side projection for t+1: runs inside the cross-block visibility gap ----
        if (t < SEQ) {
            const float* x = inp + (size_t)t * HID;
            xr = 0.0f; xz = 0.0f; xn = 0.0f;
#pragma unroll
            for (int k = 0; k < KCH; ++k) {
                float xv = x[lane + 64 * k];
                xr = fmaf(Ur[lane + 64 * k], xv, xr);
                xz = fmaf(Uz[lane + 64 * k], xv, xz);
                xn = fmaf(Un[lane + 64 * k], xv, xn);
            }
#pragma unroll
            for (int m = 32; m >= 1; m >>= 1) {
                xr += __shfl_xor(xr, m, 64);
                xz += __shfl_xor(xz, m, 64);
                xn += __shfl_xor(xn, m, 64);
            }
            xr += bxr; xz += bxz; xn += bxn;
        }
    }
}

extern "C" void kernel_launch(void* const* d_in, const int* in_sizes, int n_in,
                              void* d_out, int out_size, void* d_ws, size_t ws_size,
                              hipStream_t stream) {
    const float* inp = (const float*)d_in[0];
    const float* Wih = (const float*)d_in[1];
    const float* Whh = (const float*)d_in[2];
    const float* bih = (const float*)d_in[3];
    const float* bhh = (const float*)d_in[4];
    float* out = (float*)d_out;
    unsigned long long* slots = (unsigned long long*)d_ws;

    // zero both parity slots: tag 0 / value 0.0f == initial hidden state h0 = 0
    hipMemsetAsync(slots, 0, SLOT_WORDS * sizeof(unsigned long long), stream);

    gru_persistent<<<dim3(NBLK), dim3(TPB), 0, stream>>>(
        inp, Wih, Whh, bih, bhh, out, slots);
}